// Round 1
// baseline (100.169 us; speedup 1.0000x reference)
//
#include <hip/hip_runtime.h>

#define NSEG 64
#define NROW 8192
#define TILE 16
#define WROW 21504

// LDS row pitches (floats), padded +4 so different rows land in different banks
// and rows stay float4-aligned.
#define P0 132   // 128 + 4
#define P1 196   // 192 + 4
#define P2 164   // 160 + 4

__global__ __launch_bounds__(256) void iil_kernel(
    const float* __restrict__ x0, const float* __restrict__ x1, const float* __restrict__ x2,
    const float* __restrict__ w, const int* __restrict__ counts,
    float* __restrict__ y0, float* __restrict__ y1, float* __restrict__ y2)
{
    __shared__ float sx0[TILE * P0];
    __shared__ float sx1[TILE * P1];
    __shared__ float sx2[TILE * P2];
    __shared__ int sstart[NSEG + 1];
    __shared__ int ssid[TILE];

    const int t = threadIdx.x;
    const int row0 = blockIdx.x * TILE;

    // ---- wave 0: prefix scan of counts -> segment starts, then per-row sid ----
    if (t < NSEG) {
        int v = counts[t];
        #pragma unroll
        for (int d = 1; d < NSEG; d <<= 1) {
            int u = __shfl_up(v, d, 64);
            if (t >= d) v += u;
        }
        sstart[t + 1] = v;
        if (t == 0) sstart[0] = 0;
    }
    if (t < TILE) {
        int r = row0 + t;
        int lo = 0, hi = NSEG;   // invariant: sstart[lo] <= r < sstart[hi]
        while (hi - lo > 1) {
            int mid = (lo + hi) >> 1;
            if (sstart[mid] <= r) lo = mid; else hi = mid;
        }
        ssid[t] = lo;
    }

    // ---- stage x tile into LDS (coalesced float4) ----
    {
        const float4* g0 = (const float4*)x0 + (size_t)row0 * 32;
        float4* s0 = (float4*)sx0;
        #pragma unroll
        for (int i = 0; i < 2; ++i) {            // 512 float4
            int idx = t + i * 256;
            int r = idx >> 5, c = idx & 31;
            s0[r * (P0 / 4) + c] = g0[idx];
        }
        const float4* g1 = (const float4*)x1 + (size_t)row0 * 48;
        float4* s1 = (float4*)sx1;
        #pragma unroll
        for (int i = 0; i < 3; ++i) {            // 768 float4
            int idx = t + i * 256;
            int r = idx / 48, c = idx - r * 48;
            s1[r * (P1 / 4) + c] = g1[idx];
        }
        const float4* g2 = (const float4*)x2 + (size_t)row0 * 40;
        float4* s2 = (float4*)sx2;
        #pragma unroll
        for (int i = 0; i < 3; ++i) {            // 640 float4
            int idx = t + i * 256;
            if (idx < 640) {
                int r = idx / 40, c = idx - r * 40;
                s2[r * (P2 / 4) + c] = g2[idx];
            }
        }
    }
    __syncthreads();

    // ---- phase 0: mul=128, dim=1.  2 rows x 4 outs per thread ----
    {
        const int og = t & 31;           // outputs og*4 .. og*4+3
        const int rg = t >> 5;           // rows rg*2, rg*2+1
        const int r0 = rg * 2, r1 = r0 + 1;
        const float* wp0 = w + (size_t)ssid[r0] * WROW + og * 4;
        const float* wp1 = w + (size_t)ssid[r1] * WROW + og * 4;
        const float* xr0 = sx0 + r0 * P0;
        const float* xr1 = sx0 + r1 * P0;
        float4 a0 = make_float4(0.f, 0.f, 0.f, 0.f);
        float4 a1 = make_float4(0.f, 0.f, 0.f, 0.f);
        #pragma unroll 4
        for (int k = 0; k < 128; ++k) {
            float xa = xr0[k];
            float xb = xr1[k];
            float4 w0v = *(const float4*)(wp0 + (size_t)k * 128);
            float4 w1v = *(const float4*)(wp1 + (size_t)k * 128);
            a0.x = fmaf(xa, w0v.x, a0.x);
            a0.y = fmaf(xa, w0v.y, a0.y);
            a0.z = fmaf(xa, w0v.z, a0.z);
            a0.w = fmaf(xa, w0v.w, a0.w);
            a1.x = fmaf(xb, w1v.x, a1.x);
            a1.y = fmaf(xb, w1v.y, a1.y);
            a1.z = fmaf(xb, w1v.z, a1.z);
            a1.w = fmaf(xb, w1v.w, a1.w);
        }
        const float c0 = 0.011048543456039806f;  // 1/(8*sqrt(128))
        float4 o0 = make_float4(a0.x * c0, a0.y * c0, a0.z * c0, a0.w * c0);
        float4 o1 = make_float4(a1.x * c0, a1.y * c0, a1.z * c0, a1.w * c0);
        *(float4*)(y0 + (size_t)(row0 + r0) * 128 + og * 4) = o0;
        *(float4*)(y0 + (size_t)(row0 + r1) * 128 + og * 4) = o1;
    }

    // ---- phase 1: mul=64, dim=3.  1 row x 4 outs x 3 dims per thread ----
    {
        const int og = t & 15;           // outputs og*4 .. og*4+3
        const int r  = t >> 4;           // row
        const float* wp = w + (size_t)ssid[r] * WROW + 16384 + og * 4;
        const float* xr = sx1 + r * P1;
        float acc[12];
        #pragma unroll
        for (int i = 0; i < 12; ++i) acc[i] = 0.f;
        #pragma unroll 4
        for (int k = 0; k < 64; ++k) {
            float xi0 = xr[k * 3 + 0];
            float xi1 = xr[k * 3 + 1];
            float xi2 = xr[k * 3 + 2];
            float4 wv = *(const float4*)(wp + (size_t)k * 64);
            acc[0]  = fmaf(wv.x, xi0, acc[0]);
            acc[1]  = fmaf(wv.x, xi1, acc[1]);
            acc[2]  = fmaf(wv.x, xi2, acc[2]);
            acc[3]  = fmaf(wv.y, xi0, acc[3]);
            acc[4]  = fmaf(wv.y, xi1, acc[4]);
            acc[5]  = fmaf(wv.y, xi2, acc[5]);
            acc[6]  = fmaf(wv.z, xi0, acc[6]);
            acc[7]  = fmaf(wv.z, xi1, acc[7]);
            acc[8]  = fmaf(wv.z, xi2, acc[8]);
            acc[9]  = fmaf(wv.w, xi0, acc[9]);
            acc[10] = fmaf(wv.w, xi1, acc[10]);
            acc[11] = fmaf(wv.w, xi2, acc[11]);
        }
        const float c1 = 0.015625f;      // 1/(8*8)
        float* yb = y1 + (size_t)(row0 + r) * 192 + og * 12;
        float4 v0 = make_float4(acc[0] * c1, acc[1] * c1, acc[2] * c1, acc[3] * c1);
        float4 v1 = make_float4(acc[4] * c1, acc[5] * c1, acc[6] * c1, acc[7] * c1);
        float4 v2 = make_float4(acc[8] * c1, acc[9] * c1, acc[10] * c1, acc[11] * c1);
        *(float4*)(yb + 0) = v0;
        *(float4*)(yb + 4) = v1;
        *(float4*)(yb + 8) = v2;
    }

    // ---- phase 2: mul=32, dim=5.  1 row x 2 outs x 5 dims per thread ----
    {
        const int og = t & 15;           // outputs og*2, og*2+1
        const int r  = t >> 4;           // row
        const float* wp = w + (size_t)ssid[r] * WROW + 20480 + og * 2;
        const float* xr = sx2 + r * P2;
        float acc[10];
        #pragma unroll
        for (int i = 0; i < 10; ++i) acc[i] = 0.f;
        #pragma unroll 4
        for (int k = 0; k < 32; ++k) {
            float xv[5];
            #pragma unroll
            for (int i = 0; i < 5; ++i) xv[i] = xr[k * 5 + i];
            float2 wv = *(const float2*)(wp + (size_t)k * 32);
            #pragma unroll
            for (int i = 0; i < 5; ++i) {
                acc[i]     = fmaf(wv.x, xv[i], acc[i]);
                acc[5 + i] = fmaf(wv.y, xv[i], acc[5 + i]);
            }
        }
        const float c2 = 0.022097086912079608f;  // 1/(8*sqrt(32))
        float* yb = y2 + (size_t)(row0 + r) * 160 + og * 10;
        #pragma unroll
        for (int i = 0; i < 5; ++i) {
            float2 v = make_float2(acc[2 * i] * c2, acc[2 * i + 1] * c2);
            *(float2*)(yb + 2 * i) = v;
        }
    }
}

extern "C" void kernel_launch(void* const* d_in, const int* in_sizes, int n_in,
                              void* d_out, int out_size, void* d_ws, size_t ws_size,
                              hipStream_t stream) {
    const float* x0 = (const float*)d_in[0];
    const float* x1 = (const float*)d_in[1];
    const float* x2 = (const float*)d_in[2];
    const float* w  = (const float*)d_in[3];
    const int* counts = (const int*)d_in[4];

    float* y0 = (float*)d_out;
    float* y1 = y0 + (size_t)NROW * 128;
    float* y2 = y1 + (size_t)NROW * 192;

    hipLaunchKernelGGL(iil_kernel, dim3(NROW / TILE), dim3(256), 0, stream,
                       x0, x1, x2, w, counts, y0, y1, y2);
}